// Round 4
// baseline (1987.808 us; speedup 1.0000x reference)
//
#include <hip/hip_runtime.h>

#define EPS 1e-5f
#define BATCH 524288
#define BLK 256
#define NBLK (BATCH / BLK)   // 2048 blocks for k_lstm
#define RBLK 256             // blocks for k_reduce_x

typedef float v4f __attribute__((ext_vector_type(4)));

// ---- weight table float offsets (slice-interleaved layout, see k_prep) ----
// column perm: j' = s*20 + d*4 + g  (s=slice 0..3, d=hdim-in-slice 0..4,
//                                    g=gate 0:i 1:f 2:g 3:o; hidden j = s*5+d)
#define OFF_IH0 0      // 4 slices * 4 k * 20
#define OFF_HH0 320    // 4 * 20 * 20
#define OFF_L1  1920   // 4 * 40 * 20   rows k<20: Wih1, k>=20: Whh1
#define OFF_B0  5120   // 80
#define OFF_B1  5200   // 80
#define WTOT    5280
// workspace offsets past the weight table
#define OFF_P1  (WTOT + 96)
#define OFF_P2  (OFF_P1 + RBLK * 12)
#define OFF_ST  (OFF_P2 + NBLK * 2)

__device__ __forceinline__ float sigm(float x) {
    return __builtin_amdgcn_rcpf(1.0f + __expf(-x));
}
__device__ __forceinline__ float tanh_f(float x) {
    return 1.0f - 2.0f * __builtin_amdgcn_rcpf(1.0f + __expf(2.0f * x));
}
__device__ __forceinline__ float wave_reduce(float v) {
    #pragma unroll
    for (int o = 32; o; o >>= 1) v += __shfl_down(v, o, 64);
    return v;
}

// one 20-wide FMA step against broadcast weight row (5 x ds_read_b128).
// macro (not function/lambda) so acc[] is never address-taken -> stays in VGPRs.
#define STEP20(BASE_, S_) do {                                         \
    float s_ = (S_);                                                   \
    _Pragma("unroll")                                                  \
    for (int q_ = 0; q_ < 5; ++q_) {                                   \
        v4f w_ = wf4[(BASE_) + q_];                                    \
        acc[4*q_ + 0] = fmaf(w_.x, s_, acc[4*q_ + 0]);                 \
        acc[4*q_ + 1] = fmaf(w_.y, s_, acc[4*q_ + 1]);                 \
        acc[4*q_ + 2] = fmaf(w_.z, s_, acc[4*q_ + 2]);                 \
        acc[4*q_ + 3] = fmaf(w_.w, s_, acc[4*q_ + 3]);                 \
    }                                                                  \
} while (0)

// activation for slice S_: acc[4d..4d+3] = (i,f,g,o) for hidden j = S_*5+d
#define ACT20(S_, CARR_, HN_) do {                                     \
    _Pragma("unroll")                                                  \
    for (int d_ = 0; d_ < 5; ++d_) {                                   \
        float ii = sigm(acc[4*d_ + 0]);                                \
        float ff = sigm(acc[4*d_ + 1]);                                \
        float gg = tanh_f(acc[4*d_ + 2]);                              \
        float oo = sigm(acc[4*d_ + 3]);                                \
        int j_ = (S_) * 5 + d_;                                        \
        CARR_[j_] = ff * CARR_[j_] + ii * gg;                          \
        HN_[j_] = oo * tanh_f(CARR_[j_]);                              \
    }                                                                  \
} while (0)

// ---------------- Kernel 0: permute weights into ws ----------------
__global__ __launch_bounds__(BLK) void k_prep(
    const float* __restrict__ Wih0, const float* __restrict__ Whh0,
    const float* __restrict__ bih0, const float* __restrict__ bhh0,
    const float* __restrict__ Wih1, const float* __restrict__ Whh1,
    const float* __restrict__ bih1, const float* __restrict__ bhh1,
    float* __restrict__ wsT) {
    int tid = threadIdx.x;
    for (int m = tid; m < 320; m += BLK) {          // IH0: row = s*4+k
        int col = m % 20, row = m / 20;
        int s = row / 4, k = row % 4;
        int d = col / 4, g = col % 4;
        wsT[OFF_IH0 + m] = Wih0[(g * 20 + s * 5 + d) * 4 + k];
    }
    for (int m = tid; m < 1600; m += BLK) {         // HH0: row = s*20+k
        int col = m % 20, row = m / 20;
        int s = row / 20, k = row % 20;
        int d = col / 4, g = col % 4;
        wsT[OFF_HH0 + m] = Whh0[(g * 20 + s * 5 + d) * 20 + k];
    }
    for (int m = tid; m < 3200; m += BLK) {         // L1: row = s*40+k
        int col = m % 20, row = m / 20;
        int s = row / 40, k = row % 40;
        int d = col / 4, g = col % 4;
        int r = g * 20 + s * 5 + d;
        wsT[OFF_L1 + m] = (k < 20) ? Wih1[r * 20 + k] : Whh1[r * 20 + (k - 20)];
    }
    for (int m = tid; m < 80; m += BLK) {           // biases
        int s = m / 20, col = m % 20;
        int d = col / 4, g = col % 4;
        int r = g * 20 + s * 5 + d;
        wsT[OFF_B0 + m] = bih0[r] + bhh0[r];
        wsT[OFF_B1 + m] = bih1[r] + bhh1[r];
    }
}

// ---------------- Kernel 1: per-channel sums of x (grid-stride) ----------------
__global__ __launch_bounds__(BLK) void k_reduce_x(const float* __restrict__ x,
                                                  float* __restrict__ part1) {
    float s[6], q[6];
    #pragma unroll
    for (int t = 0; t < 6; ++t) { s[t] = 0.f; q[t] = 0.f; }
    for (int b = blockIdx.x * BLK + threadIdx.x; b < BATCH; b += RBLK * BLK) {
        const float4* xp = (const float4*)(x + (size_t)b * 24);
        #pragma unroll
        for (int t = 0; t < 6; ++t) {
            float4 v = xp[t];
            s[t] += (v.x + v.y) + (v.z + v.w);
            q[t] += (v.x * v.x + v.y * v.y) + (v.z * v.z + v.w * v.w);
        }
    }
    __shared__ float red[4 * 12];
    int wid = threadIdx.x >> 6, lane = threadIdx.x & 63;
    #pragma unroll
    for (int c = 0; c < 6; ++c) {
        float rs = wave_reduce(s[c]);
        float rq = wave_reduce(q[c]);
        if (lane == 0) { red[wid * 12 + c] = rs; red[wid * 12 + 6 + c] = rq; }
    }
    __syncthreads();
    if (threadIdx.x < 12) {
        float tot = red[threadIdx.x] + red[12 + threadIdx.x] +
                    red[24 + threadIdx.x] + red[36 + threadIdx.x];
        part1[blockIdx.x * 12 + threadIdx.x] = tot;
    }
}

// ---------------- Kernel 2: finalize BN1 stats ----------------
__global__ __launch_bounds__(BLK) void k_stats1(const float* __restrict__ part1,
                                                const float* __restrict__ gamma,
                                                const float* __restrict__ beta,
                                                float* __restrict__ stats) {
    float acc[12];
    #pragma unroll
    for (int c = 0; c < 12; ++c) acc[c] = 0.f;
    for (int p = threadIdx.x; p < RBLK; p += BLK) {
        #pragma unroll
        for (int c = 0; c < 12; ++c) acc[c] += part1[p * 12 + c];
    }
    __shared__ float red[4 * 12];
    __shared__ float tot[12];
    int wid = threadIdx.x >> 6, lane = threadIdx.x & 63;
    #pragma unroll
    for (int c = 0; c < 12; ++c) {
        float r = wave_reduce(acc[c]);
        if (lane == 0) red[wid * 12 + c] = r;
    }
    __syncthreads();
    if (threadIdx.x < 12) {
        tot[threadIdx.x] = red[threadIdx.x] + red[12 + threadIdx.x] +
                           red[24 + threadIdx.x] + red[36 + threadIdx.x];
    }
    __syncthreads();
    if (threadIdx.x < 6) {
        int t = threadIdx.x;
        const float N = (float)BATCH * 4.0f;
        float mean = tot[t] / N;
        float var = tot[6 + t] / N - mean * mean;
        float inv = rsqrtf(var + EPS);
        float a = gamma[t] * inv;
        stats[t] = a;
        stats[6 + t] = beta[t] - mean * a;
    }
}

// ---------------- Kernel 3: fused BN1 + 2-layer LSTM + head dot ----------------
// 20-wide gate-interleaved slices: acc[20] only. Weights broadcast from LDS
// (wave-uniform ds_read_b128). h0|h1 per-thread in one LDS row (stride 41,
// odd -> conflict-free). c0/c1/h_new in registers (all statically indexed).
__global__ __launch_bounds__(BLK, 1) void k_lstm(
    const float* __restrict__ x,
    const float* __restrict__ wsT,
    const float* __restrict__ Wout,
    const float* __restrict__ stats,
    float* __restrict__ dotout, float* __restrict__ part2) {
    __shared__ __align__(16) float sWT[WTOT];   // 21120 B
    __shared__ float sHH[BLK * 41];             // 41984 B   (total 63104 B)

    const int tid = threadIdx.x;
    for (int m = tid; m < WTOT; m += BLK) sWT[m] = wsT[m];

    float sA[12];
    #pragma unroll
    for (int c = 0; c < 12; ++c) sA[c] = stats[c];   // uniform -> SGPR

    const int b = blockIdx.x * BLK + tid;
    float* hp = &sHH[tid * 41];     // [0..20) = h0, [20..40) = h1
    const v4f* wf4 = (const v4f*)sWT;

    float c0[20], c1[20];
    #pragma unroll
    for (int j = 0; j < 20; ++j) { c0[j] = 0.f; c1[j] = 0.f; }
    __syncthreads();                 // weights staged
    #pragma unroll
    for (int k = 0; k < 40; ++k) hp[k] = 0.f;

    const float4* xp = (const float4*)(x + (size_t)b * 24);
    float acc[20];
    float hn[20];

    #pragma unroll 1
    for (int t = 0; t < 6; ++t) {
        float at = sA[t], bt = sA[6 + t];
        float4 xv = xp[t];
        float xn0 = at * xv.x + bt, xn1 = at * xv.y + bt;
        float xn2 = at * xv.z + bt, xn3 = at * xv.w + bt;

        // ---- layer 0: 4 slices of 20 interleaved gate-columns ----
        #pragma unroll
        for (int s4 = 0; s4 < 4; ++s4) {
            #pragma unroll
            for (int q = 0; q < 5; ++q) {               // bias init
                v4f bq = wf4[1280 + s4 * 5 + q];
                acc[4 * q + 0] = bq.x; acc[4 * q + 1] = bq.y;
                acc[4 * q + 2] = bq.z; acc[4 * q + 3] = bq.w;
            }
            STEP20((s4 * 4 + 0) * 5, xn0);              // IH0, k static
            STEP20((s4 * 4 + 1) * 5, xn1);
            STEP20((s4 * 4 + 2) * 5, xn2);
            STEP20((s4 * 4 + 3) * 5, xn3);
            #pragma unroll 2
            for (int k = 0; k < 20; ++k)                // HH0
                STEP20(80 + (s4 * 20 + k) * 5, hp[k]);
            ACT20(s4, c0, hn);
        }
        #pragma unroll
        for (int j = 0; j < 20; ++j) hp[j] = hn[j];     // flush h0_new

        // ---- layer 1: combined [Wih1|Whh1] 40-k loop over [h0_new|h1_old] ----
        #pragma unroll
        for (int s4 = 0; s4 < 4; ++s4) {
            #pragma unroll
            for (int q = 0; q < 5; ++q) {
                v4f bq = wf4[1300 + s4 * 5 + q];
                acc[4 * q + 0] = bq.x; acc[4 * q + 1] = bq.y;
                acc[4 * q + 2] = bq.z; acc[4 * q + 3] = bq.w;
            }
            #pragma unroll 2
            for (int k = 0; k < 40; ++k)
                STEP20(480 + (s4 * 40 + k) * 5, hp[k]);
            ACT20(s4, c1, hn);
        }
        #pragma unroll
        for (int j = 0; j < 20; ++j) hp[20 + j] = hn[j];  // flush h1_new
    }

    // final h2[:,5,:] is in hn[]: head dot + BN2 partial sums
    float sum = 0.f, sumsq = 0.f, dot = 0.f;
    #pragma unroll
    for (int j = 0; j < 20; ++j) {
        float v = hn[j];
        sum += v; sumsq += v * v;
        dot = fmaf(v, Wout[j], dot);    // Wout uniform -> SGPR
    }
    dotout[b] = dot;
    sum = wave_reduce(sum);
    sumsq = wave_reduce(sumsq);
    __syncthreads();                    // all waves done with sHH rows
    float* red = sHH;
    int wid = tid >> 6, lane = tid & 63;
    if (lane == 0) { red[wid] = sum; red[4 + wid] = sumsq; }
    __syncthreads();
    if (tid == 0) {
        part2[blockIdx.x * 2 + 0] = red[0] + red[1] + red[2] + red[3];
        part2[blockIdx.x * 2 + 1] = red[4] + red[5] + red[6] + red[7];
    }
}

// ---------------- Kernel 4: finalize BN2 stats -> s1, s2 ----------------
__global__ __launch_bounds__(BLK) void k_stats2(const float* __restrict__ part2,
                                                const float* __restrict__ gamma,
                                                const float* __restrict__ beta,
                                                const float* __restrict__ Wout,
                                                const float* __restrict__ bout,
                                                float* __restrict__ stats) {
    float s = 0.f, q = 0.f;
    for (int p = threadIdx.x; p < NBLK; p += BLK) {
        s += part2[2 * p]; q += part2[2 * p + 1];
    }
    __shared__ float red[8];
    s = wave_reduce(s);
    q = wave_reduce(q);
    int wid = threadIdx.x >> 6, lane = threadIdx.x & 63;
    if (lane == 0) { red[wid] = s; red[4 + wid] = q; }
    __syncthreads();
    if (threadIdx.x == 0) {
        float S = red[0] + red[1] + red[2] + red[3];
        float Q = red[4] + red[5] + red[6] + red[7];
        const float N = (float)BATCH * 20.0f;
        float m = S / N, var = Q / N - m * m;
        float inv = rsqrtf(var + EPS);
        float s1 = gamma[5] * inv;
        float sw = 0.f;
        for (int h = 0; h < 20; ++h) sw += Wout[h];
        stats[12] = s1;
        stats[13] = (beta[5] - m * s1) * sw + bout[0];
    }
}

// ---------------- Kernel 5: out = s1*dot + s2 (in place) ----------------
__global__ __launch_bounds__(BLK) void k_out(float* __restrict__ out,
                                             const float* __restrict__ stats) {
    int i = blockIdx.x * BLK + threadIdx.x;
    out[i] = stats[12] * out[i] + stats[13];
}

extern "C" void kernel_launch(void* const* d_in, const int* in_sizes, int n_in,
                              void* d_out, int out_size, void* d_ws, size_t ws_size,
                              hipStream_t stream) {
    const float* x     = (const float*)d_in[0];
    const float* gamma = (const float*)d_in[1];
    const float* beta  = (const float*)d_in[2];
    const float* Wih0  = (const float*)d_in[3];
    const float* Whh0  = (const float*)d_in[4];
    const float* bih0  = (const float*)d_in[5];
    const float* bhh0  = (const float*)d_in[6];
    const float* Wih1  = (const float*)d_in[7];
    const float* Whh1  = (const float*)d_in[8];
    const float* bih1  = (const float*)d_in[9];
    const float* bhh1  = (const float*)d_in[10];
    const float* Wout  = (const float*)d_in[11];
    const float* bout  = (const float*)d_in[12];
    float* out = (float*)d_out;
    float* ws = (float*)d_ws;

    float* part1 = ws + OFF_P1;
    float* part2 = ws + OFF_P2;
    float* stats = ws + OFF_ST;

    k_prep<<<1, BLK, 0, stream>>>(Wih0, Whh0, bih0, bhh0,
                                  Wih1, Whh1, bih1, bhh1, ws);
    k_reduce_x<<<RBLK, BLK, 0, stream>>>(x, part1);
    k_stats1<<<1, BLK, 0, stream>>>(part1, gamma, beta, stats);
    k_lstm<<<NBLK, BLK, 0, stream>>>(x, ws, Wout, stats, out, part2);
    k_stats2<<<1, BLK, 0, stream>>>(part2, gamma, beta, Wout, bout, stats);
    k_out<<<NBLK, BLK, 0, stream>>>(out, stats);
}

// Round 5
// 738.800 us; speedup vs baseline: 2.6906x; 2.6906x over previous
//
#include <hip/hip_runtime.h>

#define EPS 1e-5f
#define BATCH 524288
#define BLK 256
#define NBLK (BATCH / BLK)   // 2048 blocks for k_lstm
#define RBLK 256             // blocks for k_reduce_x

typedef float v4f __attribute__((ext_vector_type(4)));

// ---- weight table float offsets (slice-interleaved layout, see k_prep) ----
// column perm: j' = s*20 + d*4 + g  (s=slice 0..3, d=hdim-in-slice 0..4,
//                                    g=gate 0:i 1:f 2:g 3:o; hidden j = s*5+d)
#define OFF_IH0 0      // 4 slices * 4 k * 20
#define OFF_HH0 320    // 4 * 20 * 20
#define OFF_L1  1920   // 4 * 40 * 20   rows k<20: Wih1, k>=20: Whh1
#define OFF_B0  5120   // 80
#define OFF_B1  5200   // 80
#define WTOT    5280
// workspace offsets past the weight table
#define OFF_P1  (WTOT + 96)
#define OFF_P2  (OFF_P1 + RBLK * 12)
#define OFF_ST  (OFF_P2 + NBLK * 2)

__device__ __forceinline__ float sigm(float x) {
    return __builtin_amdgcn_rcpf(1.0f + __expf(-x));
}
__device__ __forceinline__ float tanh_f(float x) {
    return 1.0f - 2.0f * __builtin_amdgcn_rcpf(1.0f + __expf(2.0f * x));
}
__device__ __forceinline__ float wave_reduce(float v) {
    #pragma unroll
    for (int o = 32; o; o >>= 1) v += __shfl_down(v, o, 64);
    return v;
}

// one 20-wide FMA step against broadcast weight row (5 x ds_read_b128).
// macro (not function/lambda) so acc[] is never address-taken -> stays in VGPRs.
#define STEP20(WT_, BASE_, S_) do {                                    \
    float s_ = (S_);                                                   \
    _Pragma("unroll")                                                  \
    for (int q_ = 0; q_ < 5; ++q_) {                                   \
        v4f w_ = (WT_)[(BASE_) + q_];                                  \
        acc[4*q_ + 0] = fmaf(w_.x, s_, acc[4*q_ + 0]);                 \
        acc[4*q_ + 1] = fmaf(w_.y, s_, acc[4*q_ + 1]);                 \
        acc[4*q_ + 2] = fmaf(w_.z, s_, acc[4*q_ + 2]);                 \
        acc[4*q_ + 3] = fmaf(w_.w, s_, acc[4*q_ + 3]);                 \
    }                                                                  \
} while (0)

// activation for slice S_: acc[4d..4d+3] = (i,f,g,o) for hidden j = S_*5+d
#define ACT20(S_, CARR_, HN_) do {                                     \
    _Pragma("unroll")                                                  \
    for (int d_ = 0; d_ < 5; ++d_) {                                   \
        float ii = sigm(acc[4*d_ + 0]);                                \
        float ff = sigm(acc[4*d_ + 1]);                                \
        float gg = tanh_f(acc[4*d_ + 2]);                              \
        float oo = sigm(acc[4*d_ + 3]);                                \
        int j_ = (S_) * 5 + d_;                                        \
        CARR_[j_] = ff * CARR_[j_] + ii * gg;                          \
        HN_[j_] = oo * tanh_f(CARR_[j_]);                              \
    }                                                                  \
} while (0)

// ---------------- Kernel 0: permute weights into ws ----------------
__global__ __launch_bounds__(BLK) void k_prep(
    const float* __restrict__ Wih0, const float* __restrict__ Whh0,
    const float* __restrict__ bih0, const float* __restrict__ bhh0,
    const float* __restrict__ Wih1, const float* __restrict__ Whh1,
    const float* __restrict__ bih1, const float* __restrict__ bhh1,
    float* __restrict__ wsT) {
    int tid = threadIdx.x;
    for (int m = tid; m < 320; m += BLK) {          // IH0: row = s*4+k
        int col = m % 20, row = m / 20;
        int s = row / 4, k = row % 4;
        int d = col / 4, g = col % 4;
        wsT[OFF_IH0 + m] = Wih0[(g * 20 + s * 5 + d) * 4 + k];
    }
    for (int m = tid; m < 1600; m += BLK) {         // HH0: row = s*20+k
        int col = m % 20, row = m / 20;
        int s = row / 20, k = row % 20;
        int d = col / 4, g = col % 4;
        wsT[OFF_HH0 + m] = Whh0[(g * 20 + s * 5 + d) * 20 + k];
    }
    for (int m = tid; m < 3200; m += BLK) {         // L1: row = s*40+k
        int col = m % 20, row = m / 20;
        int s = row / 40, k = row % 40;
        int d = col / 4, g = col % 4;
        int r = g * 20 + s * 5 + d;
        wsT[OFF_L1 + m] = (k < 20) ? Wih1[r * 20 + k] : Whh1[r * 20 + (k - 20)];
    }
    for (int m = tid; m < 80; m += BLK) {           // biases
        int s = m / 20, col = m % 20;
        int d = col / 4, g = col % 4;
        int r = g * 20 + s * 5 + d;
        wsT[OFF_B0 + m] = bih0[r] + bhh0[r];
        wsT[OFF_B1 + m] = bih1[r] + bhh1[r];
    }
}

// ---------------- Kernel 1: per-channel sums of x (grid-stride) ----------------
__global__ __launch_bounds__(BLK) void k_reduce_x(const float* __restrict__ x,
                                                  float* __restrict__ part1) {
    float s[6], q[6];
    #pragma unroll
    for (int t = 0; t < 6; ++t) { s[t] = 0.f; q[t] = 0.f; }
    for (int b = blockIdx.x * BLK + threadIdx.x; b < BATCH; b += RBLK * BLK) {
        const float4* xp = (const float4*)(x + (size_t)b * 24);
        #pragma unroll
        for (int t = 0; t < 6; ++t) {
            float4 v = xp[t];
            s[t] += (v.x + v.y) + (v.z + v.w);
            q[t] += (v.x * v.x + v.y * v.y) + (v.z * v.z + v.w * v.w);
        }
    }
    __shared__ float red[4 * 12];
    int wid = threadIdx.x >> 6, lane = threadIdx.x & 63;
    #pragma unroll
    for (int c = 0; c < 6; ++c) {
        float rs = wave_reduce(s[c]);
        float rq = wave_reduce(q[c]);
        if (lane == 0) { red[wid * 12 + c] = rs; red[wid * 12 + 6 + c] = rq; }
    }
    __syncthreads();
    if (threadIdx.x < 12) {
        float tot = red[threadIdx.x] + red[12 + threadIdx.x] +
                    red[24 + threadIdx.x] + red[36 + threadIdx.x];
        part1[blockIdx.x * 12 + threadIdx.x] = tot;
    }
}

// ---------------- Kernel 2: finalize BN1 stats ----------------
__global__ __launch_bounds__(BLK) void k_stats1(const float* __restrict__ part1,
                                                const float* __restrict__ gamma,
                                                const float* __restrict__ beta,
                                                float* __restrict__ stats) {
    float acc[12];
    #pragma unroll
    for (int c = 0; c < 12; ++c) acc[c] = 0.f;
    for (int p = threadIdx.x; p < RBLK; p += BLK) {
        #pragma unroll
        for (int c = 0; c < 12; ++c) acc[c] += part1[p * 12 + c];
    }
    __shared__ float red[4 * 12];
    __shared__ float tot[12];
    int wid = threadIdx.x >> 6, lane = threadIdx.x & 63;
    #pragma unroll
    for (int c = 0; c < 12; ++c) {
        float r = wave_reduce(acc[c]);
        if (lane == 0) red[wid * 12 + c] = r;
    }
    __syncthreads();
    if (threadIdx.x < 12) {
        tot[threadIdx.x] = red[threadIdx.x] + red[12 + threadIdx.x] +
                           red[24 + threadIdx.x] + red[36 + threadIdx.x];
    }
    __syncthreads();
    if (threadIdx.x < 6) {
        int t = threadIdx.x;
        const float N = (float)BATCH * 4.0f;
        float mean = tot[t] / N;
        float var = tot[6 + t] / N - mean * mean;
        float inv = rsqrtf(var + EPS);
        float a = gamma[t] * inv;
        stats[t] = a;
        stats[6 + t] = beta[t] - mean * a;
    }
}

// ---------------- Kernel 3: fused BN1 + 2-layer LSTM + head dot ----------------
// 20-wide gate-interleaved slices: acc[20] only. Weights broadcast from LDS
// (wave-uniform ds_read_b128, same-address fast path). Per t-iteration the
// weight base is made OPAQUE (asm) so LICM cannot hoist the 21KB table into
// registers across the t-loop (R3/R4 spill root cause). h0|h1 per-thread in
// one LDS row (stride 41, odd -> conflict-free).
__global__ __launch_bounds__(BLK, 2) void k_lstm(
    const float* __restrict__ x,
    const float* __restrict__ wsT,
    const float* __restrict__ Wout,
    const float* __restrict__ stats,
    float* __restrict__ dotout, float* __restrict__ part2) {
    __shared__ __align__(16) float sWT[WTOT];   // 21120 B
    __shared__ float sHH[BLK * 41];             // 41984 B   (total 63104 B)

    const int tid = threadIdx.x;
    for (int m = tid; m < WTOT; m += BLK) sWT[m] = wsT[m];

    float sA[12];
    #pragma unroll
    for (int c = 0; c < 12; ++c) sA[c] = stats[c];   // uniform -> SGPR

    const int b = blockIdx.x * BLK + tid;
    float* hp = &sHH[tid * 41];     // [0..20) = h0, [20..40) = h1
    const v4f* wf4 = (const v4f*)sWT;

    float c0[20], c1[20];
    #pragma unroll
    for (int j = 0; j < 20; ++j) { c0[j] = 0.f; c1[j] = 0.f; }
    __syncthreads();                 // weights staged
    #pragma unroll
    for (int k = 0; k < 40; ++k) hp[k] = 0.f;

    const float4* xp = (const float4*)(x + (size_t)b * 24);
    float acc[20];
    float hn[20];

    #pragma unroll 1
    for (int t = 0; t < 6; ++t) {
        // opaque zero offset: blocks cross-t CSE/LICM of the weight loads
        int zoff = 0;
        asm volatile("" : "+s"(zoff));
        const v4f* wt = wf4 + zoff;

        float at = sA[t], bt = sA[6 + t];
        float4 xv = xp[t];
        float xn0 = at * xv.x + bt, xn1 = at * xv.y + bt;
        float xn2 = at * xv.z + bt, xn3 = at * xv.w + bt;

        // ---- layer 0: 4 slices of 20 interleaved gate-columns ----
        #pragma unroll
        for (int s4 = 0; s4 < 4; ++s4) {
            #pragma unroll
            for (int q = 0; q < 5; ++q) {               // bias init
                v4f bq = wt[1280 + s4 * 5 + q];
                acc[4 * q + 0] = bq.x; acc[4 * q + 1] = bq.y;
                acc[4 * q + 2] = bq.z; acc[4 * q + 3] = bq.w;
            }
            STEP20(wt, (s4 * 4 + 0) * 5, xn0);          // IH0, k static
            STEP20(wt, (s4 * 4 + 1) * 5, xn1);
            STEP20(wt, (s4 * 4 + 2) * 5, xn2);
            STEP20(wt, (s4 * 4 + 3) * 5, xn3);
            #pragma unroll 2
            for (int k = 0; k < 20; ++k)                // HH0
                STEP20(wt, 80 + (s4 * 20 + k) * 5, hp[k]);
            ACT20(s4, c0, hn);
        }
        #pragma unroll
        for (int j = 0; j < 20; ++j) hp[j] = hn[j];     // flush h0_new

        // ---- layer 1: combined [Wih1|Whh1] 40-k loop over [h0_new|h1_old] ----
        #pragma unroll
        for (int s4 = 0; s4 < 4; ++s4) {
            #pragma unroll
            for (int q = 0; q < 5; ++q) {
                v4f bq = wt[1300 + s4 * 5 + q];
                acc[4 * q + 0] = bq.x; acc[4 * q + 1] = bq.y;
                acc[4 * q + 2] = bq.z; acc[4 * q + 3] = bq.w;
            }
            #pragma unroll 2
            for (int k = 0; k < 40; ++k)
                STEP20(wt, 480 + (s4 * 40 + k) * 5, hp[k]);
            ACT20(s4, c1, hn);
        }
        #pragma unroll
        for (int j = 0; j < 20; ++j) hp[20 + j] = hn[j];  // flush h1_new
    }

    // final h2[:,5,:] is in hn[]: head dot + BN2 partial sums
    float sum = 0.f, sumsq = 0.f, dot = 0.f;
    #pragma unroll
    for (int j = 0; j < 20; ++j) {
        float v = hn[j];
        sum += v; sumsq += v * v;
        dot = fmaf(v, Wout[j], dot);    // Wout uniform -> SGPR
    }
    dotout[b] = dot;
    sum = wave_reduce(sum);
    sumsq = wave_reduce(sumsq);
    __syncthreads();                    // all waves done with sHH rows
    float* red = sHH;
    int wid = tid >> 6, lane = tid & 63;
    if (lane == 0) { red[wid] = sum; red[4 + wid] = sumsq; }
    __syncthreads();
    if (tid == 0) {
        part2[blockIdx.x * 2 + 0] = red[0] + red[1] + red[2] + red[3];
        part2[blockIdx.x * 2 + 1] = red[4] + red[5] + red[6] + red[7];
    }
}

// ---------------- Kernel 4: finalize BN2 stats -> s1, s2 ----------------
__global__ __launch_bounds__(BLK) void k_stats2(const float* __restrict__ part2,
                                                const float* __restrict__ gamma,
                                                const float* __restrict__ beta,
                                                const float* __restrict__ Wout,
                                                const float* __restrict__ bout,
                                                float* __restrict__ stats) {
    float s = 0.f, q = 0.f;
    for (int p = threadIdx.x; p < NBLK; p += BLK) {
        s += part2[2 * p]; q += part2[2 * p + 1];
    }
    __shared__ float red[8];
    s = wave_reduce(s);
    q = wave_reduce(q);
    int wid = threadIdx.x >> 6, lane = threadIdx.x & 63;
    if (lane == 0) { red[wid] = s; red[4 + wid] = q; }
    __syncthreads();
    if (threadIdx.x == 0) {
        float S = red[0] + red[1] + red[2] + red[3];
        float Q = red[4] + red[5] + red[6] + red[7];
        const float N = (float)BATCH * 20.0f;
        float m = S / N, var = Q / N - m * m;
        float inv = rsqrtf(var + EPS);
        float s1 = gamma[5] * inv;
        float sw = 0.f;
        for (int h = 0; h < 20; ++h) sw += Wout[h];
        stats[12] = s1;
        stats[13] = (beta[5] - m * s1) * sw + bout[0];
    }
}

// ---------------- Kernel 5: out = s1*dot + s2 (in place) ----------------
__global__ __launch_bounds__(BLK) void k_out(float* __restrict__ out,
                                             const float* __restrict__ stats) {
    int i = blockIdx.x * BLK + threadIdx.x;
    out[i] = stats[12] * out[i] + stats[13];
}

extern "C" void kernel_launch(void* const* d_in, const int* in_sizes, int n_in,
                              void* d_out, int out_size, void* d_ws, size_t ws_size,
                              hipStream_t stream) {
    const float* x     = (const float*)d_in[0];
    const float* gamma = (const float*)d_in[1];
    const float* beta  = (const float*)d_in[2];
    const float* Wih0  = (const float*)d_in[3];
    const float* Whh0  = (const float*)d_in[4];
    const float* bih0  = (const float*)d_in[5];
    const float* bhh0  = (const float*)d_in[6];
    const float* Wih1  = (const float*)d_in[7];
    const float* Whh1  = (const float*)d_in[8];
    const float* bih1  = (const float*)d_in[9];
    const float* bhh1  = (const float*)d_in[10];
    const float* Wout  = (const float*)d_in[11];
    const float* bout  = (const float*)d_in[12];
    float* out = (float*)d_out;
    float* ws = (float*)d_ws;

    float* part1 = ws + OFF_P1;
    float* part2 = ws + OFF_P2;
    float* stats = ws + OFF_ST;

    k_prep<<<1, BLK, 0, stream>>>(Wih0, Whh0, bih0, bhh0,
                                  Wih1, Whh1, bih1, bhh1, ws);
    k_reduce_x<<<RBLK, BLK, 0, stream>>>(x, part1);
    k_stats1<<<1, BLK, 0, stream>>>(part1, gamma, beta, stats);
    k_lstm<<<NBLK, BLK, 0, stream>>>(x, ws, Wout, stats, out, part2);
    k_stats2<<<1, BLK, 0, stream>>>(part2, gamma, beta, Wout, bout, stats);
    k_out<<<NBLK, BLK, 0, stream>>>(out, stats);
}

// Round 6
// 331.585 us; speedup vs baseline: 5.9949x; 2.2281x over previous
//
#include <hip/hip_runtime.h>

#define EPS 1e-5f
#define BATCH 524288
#define BLK 256
#define RBLK 256             // blocks for k_reduce_x
#define NBLK2 4096           // k_lstm blocks (128 batch each)
#define NBLKO 2048           // k_out blocks

typedef float f32x4 __attribute__((ext_vector_type(4)));
typedef __bf16 bf16x8 __attribute__((ext_vector_type(8)));
typedef __bf16 bf16x4 __attribute__((ext_vector_type(4)));

// ---- ws layout ----
// ushort A-fragment tables occupy float [0, 5760)
#define AF_A0    0           // 10 frags x 512 ushort (layer0, tm*2+s)
#define AF_A1K0  5120        // 10 frags x 512
#define AF_A1K1  10240       // 10 frags x 128 (lanes 0..31, i<4 compressed)
#define AF_TOT   11520
#define OFF_BIAS0 5760       // 80 floats, perm j = tm*16+q*4+g
#define OFF_BIAS1 5840       // 80
#define OFF_ST    5920       // 16: a[6], b[6], s1, s2
#define OFF_P1    5936       // RBLK*12
#define OFF_P2    (OFF_P1 + RBLK * 12)   // NBLK2*2

__device__ __forceinline__ float sigm(float x) {
    return __builtin_amdgcn_rcpf(1.0f + __expf(-x));
}
__device__ __forceinline__ float tanh_f(float x) {
    return 1.0f - 2.0f * __builtin_amdgcn_rcpf(1.0f + __expf(2.0f * x));
}
__device__ __forceinline__ float wave_reduce(float v) {
    #pragma unroll
    for (int o = 32; o; o >>= 1) v += __shfl_down(v, o, 64);
    return v;
}

struct HiLo { bf16x8 hi, lo; };
__device__ __forceinline__ HiLo cvt8(f32x4 a, f32x4 b) {
    HiLo r;
    #pragma unroll
    for (int i = 0; i < 4; ++i) {
        float v = a[i];
        __bf16 h = (__bf16)v;
        r.hi[i] = h; r.lo[i] = (__bf16)(v - (float)h);
        float w = b[i];
        __bf16 h2 = (__bf16)w;
        r.hi[4 + i] = h2; r.lo[4 + i] = (__bf16)(w - (float)h2);
    }
    return r;
}
__device__ __forceinline__ bf16x8 zb8() {
    bf16x8 z;
    #pragma unroll
    for (int i = 0; i < 8; ++i) z[i] = (__bf16)0.f;
    return z;
}
#define MFMA16(C_, A_, B_) \
    (C_) = __builtin_amdgcn_mfma_f32_16x16x32_bf16((A_), (B_), (C_), 0, 0, 0)

// ---------------- Kernel 0: build A-fragments + permuted biases ----------------
// Column perm: C/D row rr = 4*q + g  <->  (d = 4*tm + q, gate g); wrow = g*20 + d.
// Fragment element i of lane l:  k = 4*(l>>4) + (i&3) + 16*(i>>2), m-row = l&15.
// Layer0 k-map: k<20 -> Whh0[.][k] (h0), k<24 -> Wih0[.][k-20] (x), else 0.
// Layer1 k-map: k<20 -> Wih1[.][k] (h0new), 20<=k<40 -> Whh1[.][k-20] (h1), else 0.
__global__ __launch_bounds__(BLK) void k_prep(
    const float* __restrict__ Wih0, const float* __restrict__ Whh0,
    const float* __restrict__ bih0, const float* __restrict__ bhh0,
    const float* __restrict__ Wih1, const float* __restrict__ Whh1,
    const float* __restrict__ bih1, const float* __restrict__ bhh1,
    float* __restrict__ ws) {
    const int tid = threadIdx.x;
    unsigned short* af = (unsigned short*)ws;
    for (int idx = tid; idx < AF_TOT; idx += BLK) {
        float w; int s;
        if (idx < AF_A1K0) {                 // layer0
            int e = idx, fid = e >> 9; e &= 511;
            int l = e >> 3, i = e & 7;
            int tm = fid >> 1; s = fid & 1;
            int q = l >> 4, m = l & 15;
            int wrow = (m & 3) * 20 + 4 * tm + (m >> 2);
            int k = 4 * q + (i & 3) + 16 * (i >> 2);
            w = (k < 20) ? Whh0[wrow * 20 + k]
              : (k < 24) ? Wih0[wrow * 4 + (k - 20)] : 0.f;
        } else if (idx < AF_A1K1) {          // layer1 K-tile0 (k 0..31)
            int e = idx - AF_A1K0, fid = e >> 9; e &= 511;
            int l = e >> 3, i = e & 7;
            int tm = fid >> 1; s = fid & 1;
            int q = l >> 4, m = l & 15;
            int wrow = (m & 3) * 20 + 4 * tm + (m >> 2);
            int k = 4 * q + (i & 3) + 16 * (i >> 2);
            w = (k < 20) ? Wih1[wrow * 20 + k] : Whh1[wrow * 20 + (k - 20)];
        } else {                             // layer1 K-tile1 (k=32+4q+i, q<2, i<4)
            int e = idx - AF_A1K1, fid = e >> 7; e &= 127;
            int l = e >> 2, i = e & 3;
            int tm = fid >> 1; s = fid & 1;
            int q = l >> 4, m = l & 15;
            int wrow = (m & 3) * 20 + 4 * tm + (m >> 2);
            int wcol = 12 + 4 * q + i;       // = k - 20, guaranteed < 20
            w = Whh1[wrow * 20 + wcol];
        }
        float fh = (float)(__bf16)w;
        float v = s ? (w - fh) : w;
        __bf16 bv = (__bf16)v;
        af[idx] = __builtin_bit_cast(unsigned short, bv);
    }
    for (int j = tid; j < 80; j += BLK) {
        int tm = j >> 4, q = (j >> 2) & 3, g = j & 3;
        int wrow = g * 20 + 4 * tm + q;
        ws[OFF_BIAS0 + j] = bih0[wrow] + bhh0[wrow];
        ws[OFF_BIAS1 + j] = bih1[wrow] + bhh1[wrow];
    }
}

// ---------------- Kernel 1: per-channel sums of x (grid-stride) ----------------
__global__ __launch_bounds__(BLK) void k_reduce_x(const float* __restrict__ x,
                                                  float* __restrict__ part1) {
    float s[6], q[6];
    #pragma unroll
    for (int t = 0; t < 6; ++t) { s[t] = 0.f; q[t] = 0.f; }
    for (int b = blockIdx.x * BLK + threadIdx.x; b < BATCH; b += RBLK * BLK) {
        const float4* xp = (const float4*)(x + (size_t)b * 24);
        #pragma unroll
        for (int t = 0; t < 6; ++t) {
            float4 v = xp[t];
            s[t] += (v.x + v.y) + (v.z + v.w);
            q[t] += (v.x * v.x + v.y * v.y) + (v.z * v.z + v.w * v.w);
        }
    }
    __shared__ float red[4 * 12];
    int wid = threadIdx.x >> 6, lane = threadIdx.x & 63;
    #pragma unroll
    for (int c = 0; c < 6; ++c) {
        float rs = wave_reduce(s[c]);
        float rq = wave_reduce(q[c]);
        if (lane == 0) { red[wid * 12 + c] = rs; red[wid * 12 + 6 + c] = rq; }
    }
    __syncthreads();
    if (threadIdx.x < 12) {
        float tot = red[threadIdx.x] + red[12 + threadIdx.x] +
                    red[24 + threadIdx.x] + red[36 + threadIdx.x];
        part1[blockIdx.x * 12 + threadIdx.x] = tot;
    }
}

// ---------------- Kernel 2: finalize BN1 stats ----------------
__global__ __launch_bounds__(BLK) void k_stats1(const float* __restrict__ part1,
                                                const float* __restrict__ gamma,
                                                const float* __restrict__ beta,
                                                float* __restrict__ stats) {
    float acc[12];
    #pragma unroll
    for (int c = 0; c < 12; ++c) acc[c] = 0.f;
    for (int p = threadIdx.x; p < RBLK; p += BLK) {
        #pragma unroll
        for (int c = 0; c < 12; ++c) acc[c] += part1[p * 12 + c];
    }
    __shared__ float red[4 * 12];
    __shared__ float tot[12];
    int wid = threadIdx.x >> 6, lane = threadIdx.x & 63;
    #pragma unroll
    for (int c = 0; c < 12; ++c) {
        float r = wave_reduce(acc[c]);
        if (lane == 0) red[wid * 12 + c] = r;
    }
    __syncthreads();
    if (threadIdx.x < 12) {
        tot[threadIdx.x] = red[threadIdx.x] + red[12 + threadIdx.x] +
                           red[24 + threadIdx.x] + red[36 + threadIdx.x];
    }
    __syncthreads();
    if (threadIdx.x < 6) {
        int t = threadIdx.x;
        const float N = (float)BATCH * 4.0f;
        float mean = tot[t] / N;
        float var = tot[6 + t] / N - mean * mean;
        float inv = rsqrtf(var + EPS);
        float a = gamma[t] * inv;
        stats[t] = a;
        stats[6 + t] = beta[t] - mean * a;
    }
}

// ---------------- Kernel 3: MFMA LSTM ----------------
// Per wave: 32 batch (2 N-tiles of 16). 5 M-tiles cover 80 gate rows.
// Cell update is lane-local (C/D row perm). h round-trips via per-wave
// transposed bounce buf [col][k], stride 44 (16B-aligned b128 reads).
// Bounce rows: 0..19 h0, 20..39 h1, 40..43 x_t.
__global__ __launch_bounds__(BLK, 3) void k_lstm(
    const float* __restrict__ x,
    const float* __restrict__ wsT,
    const float* __restrict__ Wout,
    const float* __restrict__ stats,
    float* __restrict__ dotout, float* __restrict__ part2) {
    __shared__ __align__(16) unsigned short sAF[AF_TOT];  // 23040 B
    __shared__ __align__(16) float sBias[160];            // 640 B
    __shared__ __align__(16) float sBounce[4 * 1408];     // 22528 B

    const int tid = threadIdx.x;
    {
        const unsigned int* src = (const unsigned int*)wsT;
        unsigned int* dst = (unsigned int*)sAF;
        for (int m = tid; m < AF_TOT / 2; m += BLK) dst[m] = src[m];
        for (int m = tid; m < 160; m += BLK) sBias[m] = wsT[OFF_BIAS0 + m];
    }
    float sA[12];
    #pragma unroll
    for (int c = 0; c < 12; ++c) sA[c] = stats[c];   // uniform -> SGPR

    const int wid = tid >> 6, lane = tid & 63;
    const int q = lane >> 4, col = lane & 15;
    const int wb = blockIdx.x * 128 + wid * 32;
    float* buf = sBounce + wid * 1408;
    float* bc0 = buf + col * 44;          // N-tile 0 column base
    float* bc1 = bc0 + 16 * 44;           // N-tile 1

    __syncthreads();
    for (int m = lane; m < 1408; m += 64) buf[m] = 0.f;

    float c0s[5][2], c1s[5][2], h1v[5][2];
    #pragma unroll
    for (int tm = 0; tm < 5; ++tm)
        #pragma unroll
        for (int nt = 0; nt < 2; ++nt) { c0s[tm][nt] = 0.f; c1s[tm][nt] = 0.f; h1v[tm][nt] = 0.f; }

    const float* xb0 = x + (size_t)(wb + col) * 24 + q;
    const float* xb1 = x + (size_t)(wb + 16 + col) * 24 + q;

    #pragma unroll 1
    for (int t = 0; t < 6; ++t) {
        // opaque zero offset: block cross-t LICM of the LDS weight tables (R5 fix)
        int zo = 0;
        asm volatile("" : "+s"(zo));
        const unsigned short* AF = sAF + zo;
        const float* BI = sBias + zo;

        float at = sA[t], bt = sA[6 + t];
        bc0[40 + q] = fmaf(at, xb0[t * 4], bt);   // x rows 40..43 (f = q)
        bc1[40 + q] = fmaf(at, xb1[t * 4], bt);

        // ---- layer 0: B frags (k: h0 rows 4q / half2 q==0->16, q==1->x@40) ----
        HiLo b0[2];
        #pragma unroll
        for (int nt = 0; nt < 2; ++nt) {
            const float* bp = nt ? bc1 : bc0;
            f32x4 va = *(const f32x4*)(bp + 4 * q);
            f32x4 vb = {0.f, 0.f, 0.f, 0.f};
            if (q < 2) vb = *(const f32x4*)(bp + (q ? 40 : 16));
            b0[nt] = cvt8(va, vb);
        }
        #pragma unroll
        for (int tm = 0; tm < 5; ++tm) {
            f32x4 bias = *(const f32x4*)(BI + tm * 16 + q * 4);
            bf16x8 ahi = *(const bf16x8*)(AF + AF_A0 + (2 * tm) * 512 + lane * 8);
            bf16x8 alo = *(const bf16x8*)(AF + AF_A0 + (2 * tm + 1) * 512 + lane * 8);
            #pragma unroll
            for (int nt = 0; nt < 2; ++nt) {
                f32x4 c = bias;
                MFMA16(c, ahi, b0[nt].hi);
                MFMA16(c, ahi, b0[nt].lo);
                MFMA16(c, alo, b0[nt].hi);
                float ii = sigm(c[0]), ff = sigm(c[1]);
                float gg = tanh_f(c[2]), oo = sigm(c[3]);
                float cn = fmaf(ff, c0s[tm][nt], ii * gg);
                c0s[tm][nt] = cn;
                float h = oo * tanh_f(cn);
                (nt ? bc1 : bc0)[4 * tm + q] = h;     // h0 rows 0..19
            }
        }

        // ---- layer 1: B frags (rows = k directly; K-tile1 half1 q<2 only) ----
        HiLo b1[2], b2[2];
        #pragma unroll
        for (int nt = 0; nt < 2; ++nt) {
            const float* bp = nt ? bc1 : bc0;
            f32x4 va = *(const f32x4*)(bp + 4 * q);
            f32x4 vb = *(const f32x4*)(bp + 16 + 4 * q);
            b1[nt] = cvt8(va, vb);
            f32x4 vc = {0.f, 0.f, 0.f, 0.f};
            if (q < 2) vc = *(const f32x4*)(bp + 32 + 4 * q);
            f32x4 vz = {0.f, 0.f, 0.f, 0.f};
            b2[nt] = cvt8(vc, vz);
        }
        #pragma unroll
        for (int tm = 0; tm < 5; ++tm) {
            f32x4 bias = *(const f32x4*)(BI + 80 + tm * 16 + q * 4);
            bf16x8 ahi0 = *(const bf16x8*)(AF + AF_A1K0 + (2 * tm) * 512 + lane * 8);
            bf16x8 alo0 = *(const bf16x8*)(AF + AF_A1K0 + (2 * tm + 1) * 512 + lane * 8);
            bf16x8 ahi1 = zb8(), alo1 = zb8();
            if (q < 2) {
                bf16x4 th = *(const bf16x4*)(AF + AF_A1K1 + (2 * tm) * 128 + lane * 4);
                bf16x4 tl = *(const bf16x4*)(AF + AF_A1K1 + (2 * tm + 1) * 128 + lane * 4);
                #pragma unroll
                for (int i = 0; i < 4; ++i) { ahi1[i] = th[i]; alo1[i] = tl[i]; }
            }
            #pragma unroll
            for (int nt = 0; nt < 2; ++nt) {
                f32x4 c = bias;
                MFMA16(c, ahi0, b1[nt].hi);
                MFMA16(c, ahi0, b1[nt].lo);
                MFMA16(c, alo0, b1[nt].hi);
                MFMA16(c, ahi1, b2[nt].hi);
                MFMA16(c, ahi1, b2[nt].lo);
                MFMA16(c, alo1, b2[nt].hi);
                float ii = sigm(c[0]), ff = sigm(c[1]);
                float gg = tanh_f(c[2]), oo = sigm(c[3]);
                float cn = fmaf(ff, c1s[tm][nt], ii * gg);
                c1s[tm][nt] = cn;
                float h = oo * tanh_f(cn);
                h1v[tm][nt] = h;
                (nt ? bc1 : bc0)[20 + 4 * tm + q] = h;  // h1 rows 20..39
            }
        }
    }

    // ---- epilogue: head dot + BN2 partials from final h1 ----
    float wout[5];
    #pragma unroll
    for (int tm = 0; tm < 5; ++tm) wout[tm] = Wout[4 * tm + q];
    float psum = 0.f, psq = 0.f;
    float dsum[2];
    #pragma unroll
    for (int nt = 0; nt < 2; ++nt) {
        float d = 0.f;
        #pragma unroll
        for (int tm = 0; tm < 5; ++tm) {
            float v = h1v[tm][nt];
            d = fmaf(v, wout[tm], d);
            psum += v; psq = fmaf(v, v, psq);
        }
        d += __shfl_xor(d, 16);
        d += __shfl_xor(d, 32);
        dsum[nt] = d;
    }
    if (q == 0) {
        dotout[wb + col] = dsum[0];
        dotout[wb + 16 + col] = dsum[1];
    }
    psum = wave_reduce(psum);
    psq = wave_reduce(psq);
    __syncthreads();                       // all waves done with bounce
    if (lane == 0) { sBounce[wid] = psum; sBounce[4 + wid] = psq; }
    __syncthreads();
    if (tid == 0) {
        part2[blockIdx.x * 2 + 0] = sBounce[0] + sBounce[1] + sBounce[2] + sBounce[3];
        part2[blockIdx.x * 2 + 1] = sBounce[4] + sBounce[5] + sBounce[6] + sBounce[7];
    }
}

// ---------------- Kernel 4: finalize BN2 stats -> s1, s2 ----------------
__global__ __launch_bounds__(BLK) void k_stats2(const float* __restrict__ part2,
                                                const float* __restrict__ gamma,
                                                const float* __restrict__ beta,
                                                const float* __restrict__ Wout,
                                                const float* __restrict__ bout,
                                                float* __restrict__ stats) {
    float s = 0.f, q = 0.f;
    for (int p = threadIdx.x; p < NBLK2; p += BLK) {
        s += part2[2 * p]; q += part2[2 * p + 1];
    }
    __shared__ float red[8];
    s = wave_reduce(s);
    q = wave_reduce(q);
    int wid = threadIdx.x >> 6, lane = threadIdx.x & 63;
    if (lane == 0) { red[wid] = s; red[4 + wid] = q; }
    __syncthreads();
    if (threadIdx.x == 0) {
        float S = red[0] + red[1] + red[2] + red[3];
        float Q = red[4] + red[5] + red[6] + red[7];
        const float N = (float)BATCH * 20.0f;
        float m = S / N, var = Q / N - m * m;
        float inv = rsqrtf(var + EPS);
        float s1 = gamma[5] * inv;
        float sw = 0.f;
        for (int h = 0; h < 20; ++h) sw += Wout[h];
        stats[12] = s1;
        stats[13] = (beta[5] - m * s1) * sw + bout[0];
    }
}

// ---------------- Kernel 5: out = s1*dot + s2 (in place) ----------------
__global__ __launch_bounds__(BLK) void k_out(float* __restrict__ out,
                                             const float* __restrict__ stats) {
    int i = blockIdx.x * BLK + threadIdx.x;
    out[i] = stats[12] * out[i] + stats[13];
}

extern "C" void kernel_launch(void* const* d_in, const int* in_sizes, int n_in,
                              void* d_out, int out_size, void* d_ws, size_t ws_size,
                              hipStream_t stream) {
    const float* x     = (const float*)d_in[0];
    const float* gamma = (const float*)d_in[1];
    const float* beta  = (const float*)d_in[2];
    const float* Wih0  = (const float*)d_in[3];
    const float* Whh0  = (const float*)d_in[4];
    const float* bih0  = (const float*)d_in[5];
    const float* bhh0  = (const float*)d_in[6];
    const float* Wih1  = (const float*)d_in[7];
    const float* Whh1  = (const float*)d_in[8];
    const float* bih1  = (const float*)d_in[9];
    const float* bhh1  = (const float*)d_in[10];
    const float* Wout  = (const float*)d_in[11];
    const float* bout  = (const float*)d_in[12];
    float* out = (float*)d_out;
    float* ws = (float*)d_ws;

    float* part1 = ws + OFF_P1;
    float* part2 = ws + OFF_P2;
    float* stats = ws + OFF_ST;

    k_prep<<<1, BLK, 0, stream>>>(Wih0, Whh0, bih0, bhh0,
                                  Wih1, Whh1, bih1, bhh1, ws);
    k_reduce_x<<<RBLK, BLK, 0, stream>>>(x, part1);
    k_stats1<<<1, BLK, 0, stream>>>(part1, gamma, beta, stats);
    k_lstm<<<NBLK2, BLK, 0, stream>>>(x, ws, Wout, stats, out, part2);
    k_stats2<<<1, BLK, 0, stream>>>(part2, gamma, beta, Wout, bout, stats);
    k_out<<<NBLKO, BLK, 0, stream>>>(out, stats);
}